// Round 12
// baseline (457.001 us; speedup 1.0000x reference)
//
#include <hip/hip_runtime.h>
#include <cstdint>
#include <cstddef>

#define Tn 1024
#define Bn 64
#define Cn 8
#define Nn 64
#define LDP 65             /* padded row stride for trans_lds */
#define TBC 512            /* tags stride per t */
#define ES 32768           /* emissions stride per t (B*C*N) */
#define GS ((size_t)4 * ES)  /* group stride: 4 t-slices */
#define LN2F 0.69314718056f

typedef float f32x2 __attribute__((ext_vector_type(2)));
typedef float f32x4 __attribute__((ext_vector_type(4)));

// ---- wave64 reductions via DPP ----
__device__ __forceinline__ float wred_max(float x) {
  int v;
#define STEP(ctrl) \
  v = __builtin_amdgcn_update_dpp((int)0xff800000, __float_as_int(x), ctrl, 0xf, 0xf, false); \
  x = fmaxf(x, __int_as_float(v));
  STEP(0x111) STEP(0x112) STEP(0x114) STEP(0x118) STEP(0x142) STEP(0x143)
#undef STEP
  return __int_as_float(__builtin_amdgcn_readlane(__float_as_int(x), 63));
}

__device__ __forceinline__ float wred_sum(float x) {
  int v;
#define STEP(ctrl) \
  v = __builtin_amdgcn_update_dpp(0, __float_as_int(x), ctrl, 0xf, 0xf, false); \
  x = x + __int_as_float(v);
  STEP(0x111) STEP(0x112) STEP(0x114) STEP(0x118) STEP(0x142) STEP(0x143)
#undef STEP
  return __int_as_float(__builtin_amdgcn_readlane(__float_as_int(x), 63));
}

__device__ __forceinline__ float lane0(float x) {
  return __int_as_float(__builtin_amdgcn_readlane(__float_as_int(x), 0));
}

// ---- r8-verified uniform-broadcast matvec quads (16 ds_read_b128, all lanes
// same address -> conflict-free broadcast; P2 fragments never address-taken) ----
#define MQF(q, a, b) { f32x4 t_ = eqf_[q]; \
  a += __builtin_shufflevector(t_, t_, 0, 1) * P2f[2*(q)]; \
  b += __builtin_shufflevector(t_, t_, 2, 3) * P2f[2*(q)+1]; }
#define MQB(q, a, b) { f32x4 t_ = eqb_[q]; \
  a += __builtin_shufflevector(t_, t_, 0, 1) * P2b[2*(q)]; \
  b += __builtin_shufflevector(t_, t_, 2, 3) * P2b[2*(q)+1]; }

// Fused body: both directions' reads/FMA chains interleaved for ILP.
#define MVBODY2() \
  f32x2 Af0_ = {0.f,0.f}, Af1_ = Af0_, Af2_ = Af0_, Af3_ = Af0_; \
  f32x2 Ab0_ = Af0_, Ab1_ = Af0_, Ab2_ = Af0_, Ab3_ = Af0_; \
  { const f32x4* eqf_ = (const f32x4*)ewf; \
    const f32x4* eqb_ = (const f32x4*)ewb; \
    MQF(0,Af0_,Af1_)  MQB(0,Ab0_,Ab1_)  MQF(1,Af2_,Af3_)  MQB(1,Ab2_,Ab3_) \
    MQF(2,Af0_,Af1_)  MQB(2,Ab0_,Ab1_)  MQF(3,Af2_,Af3_)  MQB(3,Ab2_,Ab3_) \
    MQF(4,Af0_,Af1_)  MQB(4,Ab0_,Ab1_)  MQF(5,Af2_,Af3_)  MQB(5,Ab2_,Ab3_) \
    MQF(6,Af0_,Af1_)  MQB(6,Ab0_,Ab1_)  MQF(7,Af2_,Af3_)  MQB(7,Ab2_,Ab3_) \
    MQF(8,Af0_,Af1_)  MQB(8,Ab0_,Ab1_)  MQF(9,Af2_,Af3_)  MQB(9,Ab2_,Ab3_) \
    MQF(10,Af0_,Af1_) MQB(10,Ab0_,Ab1_) MQF(11,Af2_,Af3_) MQB(11,Ab2_,Ab3_) \
    MQF(12,Af0_,Af1_) MQB(12,Ab0_,Ab1_) MQF(13,Af2_,Af3_) MQB(13,Ab2_,Ab3_) \
    MQF(14,Af0_,Af1_) MQB(14,Ab0_,Ab1_) MQF(15,Af2_,Af3_) MQB(15,Ab2_,Ab3_) } \
  f32x2 Sf_ = (Af0_ + Af1_) + (Af2_ + Af3_), Sb_ = (Ab0_ + Ab1_) + (Ab2_ + Ab3_); \
  float sf_ = Sf_.x + Sf_.y, sb_ = Sb_.x + Sb_.y;

#define MVBODY_F() \
  f32x2 Af0_ = {0.f,0.f}, Af1_ = Af0_, Af2_ = Af0_, Af3_ = Af0_; \
  { const f32x4* eqf_ = (const f32x4*)ewf; \
    MQF(0,Af0_,Af1_)  MQF(1,Af2_,Af3_)  MQF(2,Af0_,Af1_)  MQF(3,Af2_,Af3_) \
    MQF(4,Af0_,Af1_)  MQF(5,Af2_,Af3_)  MQF(6,Af0_,Af1_)  MQF(7,Af2_,Af3_) \
    MQF(8,Af0_,Af1_)  MQF(9,Af2_,Af3_)  MQF(10,Af0_,Af1_) MQF(11,Af2_,Af3_) \
    MQF(12,Af0_,Af1_) MQF(13,Af2_,Af3_) MQF(14,Af0_,Af1_) MQF(15,Af2_,Af3_) } \
  f32x2 Sf_ = (Af0_ + Af1_) + (Af2_ + Af3_); \
  float sf_ = Sf_.x + Sf_.y;

#define MVBODY_B() \
  f32x2 Ab0_ = {0.f,0.f}, Ab1_ = Ab0_, Ab2_ = Ab0_, Ab3_ = Ab0_; \
  { const f32x4* eqb_ = (const f32x4*)ewb; \
    MQB(0,Ab0_,Ab1_)  MQB(1,Ab2_,Ab3_)  MQB(2,Ab0_,Ab1_)  MQB(3,Ab2_,Ab3_) \
    MQB(4,Ab0_,Ab1_)  MQB(5,Ab2_,Ab3_)  MQB(6,Ab0_,Ab1_)  MQB(7,Ab2_,Ab3_) \
    MQB(8,Ab0_,Ab1_)  MQB(9,Ab2_,Ab3_)  MQB(10,Ab0_,Ab1_) MQB(11,Ab2_,Ab3_) \
    MQB(12,Ab0_,Ab1_) MQB(13,Ab2_,Ab3_) MQB(14,Ab0_,Ab1_) MQB(15,Ab2_,Ab3_) } \
  f32x2 Sb_ = (Ab0_ + Ab1_) + (Ab2_ + Ab3_); \
  float sb_ = Sb_.x + Sb_.y;

// Fused step: fwd u'_j = wf_j * sum_i P_ij u_i ; bwd v_i = sum_j P_ij (wb_j v_j)
#define DSTEP(u, v, wf, wb) do {                    \
    ewf[lane] = (u);                                \
    ewb[lane] = (v) * (wb);                         \
    MVBODY2();                                      \
    (u) = sf_ * (wf);                               \
    (v) = sb_;                                      \
  } while (0)

#define FSTEP_LIN(u, wf) do {                       \
    ewf[lane] = (u);                                \
    MVBODY_F();                                     \
    (u) = sf_ * (wf);                               \
  } while (0)

#define BSTEP_LIN(v, wb) do {                       \
    ewb[lane] = (v) * (wb);                         \
    MVBODY_B();                                     \
    (v) = sb_;                                      \
  } while (0)

// r8-verified per-group rescale (lane0 exponent, exact 2^-k, integer Lk).
#define RESCALE0(u, Lk) do {                        \
    int ke_ = (__builtin_amdgcn_readlane(__float_as_int(u), 0) >> 23) & 255; \
    (Lk) += ke_ - 127;                              \
    (u) *= __int_as_float((254 - ke_) << 23);       \
  } while (0)

// Exact max-based rescale (epilogue only).
#define RESCALE(u, Lk) do {                         \
    float mx_ = wred_max(u);                        \
    int ke_ = (__float_as_int(mx_) >> 23) & 255;    \
    (Lk) += ke_ - 127;                              \
    (u) *= __int_as_float((254 - ke_) << 23);       \
  } while (0)

__global__ __launch_bounds__(64)
void crf_fwd(const float* __restrict__ em, const int* __restrict__ tags,
             const int* __restrict__ lengths, const float* __restrict__ trans,
             const float* __restrict__ head, const float* __restrict__ tail,
             float* __restrict__ out) {
  __shared__ float trans_lds[Nn * LDP];               // 16.6 KB
  __shared__ __align__(16) float ringf[4 * 4 * Nn];   // fwd em ring (4 KB)
  __shared__ __align__(16) float ringb[4 * 4 * Nn];   // bwd em ring (4 KB)
  __shared__ __align__(16) float ewf[Nn];             // fwd broadcast buffer
  __shared__ __align__(16) float ewb[Nn];             // bwd broadcast buffer

  const int bid = blockIdx.x;                         // 512 = B*C chains, 1 wave each
  const int b = bid >> 3, c = bid & 7;
  const int lane = threadIdx.x;                       // 0..63
  const int bc = b * Cn + c;
  const int len = lengths[b];                         // [512, 1024]
  const int m = len >> 1;

  // ---- stage transitions[c] into LDS, stride 65 ----
  const float* tc = trans + c * Nn * Nn;
  for (int k = lane; k < Nn * Nn; k += 64) trans_lds[(k >> 6) * LDP + (k & 63)] = tc[k];
  __syncthreads();

  // ---- log_scores phase (single wave, 16 strips) ----
  float sc = 0.f;
#pragma unroll
  for (int it = 0; it < 16; ++it) {
    int t = it * 64 + lane;
    if (t < len) {
      int tagc = tags[t * TBC + bc];
      sc += em[(size_t)t * ES + (size_t)bc * Nn + tagc];
      if (t >= 1) {
        int tagp = tags[(t - 1) * TBC + bc];
        sc += trans_lds[tagp * LDP + tagc];
      }
    }
  }
  sc = wred_sum(sc);                                  // broadcast total
  int tag0 = tags[bc];
  int tagl = tags[(len - 1) * TBC + bc];
  float sc_ht = head[c * Nn + tag0] + tail[c * Nn + tagl];

  // ---- both P fragments in VGPRs (r8 layout, conflict-free padded reads) ----
  f32x2 P2f[32], P2b[32];
#pragma unroll
  for (int k = 0; k < 32; ++k) {
    f32x2 p;
    p.x = __expf(trans_lds[(2 * k) * LDP + lane]);    // fwd: column `lane`
    p.y = __expf(trans_lds[(2 * k + 1) * LDP + lane]);
    P2f[k] = p;
    f32x2 q;
    q.x = __expf(trans_lds[lane * LDP + 2 * k]);      // bwd: row `lane`
    q.y = __expf(trans_lds[lane * LDP + 2 * k + 1]);
    P2b[k] = q;
  }

  // ---- init both states ----
  float al0 = head[c * Nn + lane] + em[(size_t)bc * Nn + lane];
  float shf = lane0(al0);
  float u = __expf(al0 - shf);                        // fwd state (linear)
  float tl = tail[c * Nn + lane];
  float shb = lane0(tl);
  float v = __expf(tl - shb);                         // bwd state (linear)
  int Lkf = 0, Lkb = 0;

  const int nsf = m,           Gf = nsf >> 2, rf = nsf & 3;   // fwd steps
  const int nsb = len - 1 - m, Gb = nsb >> 2, rb = nsb & 3;   // bwd steps (nsb <= nsf)
  const int Gmin = (Gf < Gb) ? Gf : Gb;

  const float* g4f = em + (size_t)(1 + (lane >> 4)) * ES + (size_t)bc * Nn + ((lane & 15) << 2);
  const float* g4b = em + (size_t)(len - 1 - (lane >> 4)) * ES + (size_t)bc * Nn + ((lane & 15) << 2);

  // ---- prologue: stage groups 0,1; hold group 2 in regs ----
  float4 vf0 = *(const float4*)(g4f);
  float4 vf1 = *(const float4*)(g4f + GS);
  float4 AstF = *(const float4*)(g4f + 2 * GS);
  *(float4*)&ringf[0 * 256 + lane * 4] = vf0;
  *(float4*)&ringf[1 * 256 + lane * 4] = vf1;
  float4 vb0 = *(const float4*)(g4b);
  float4 vb1 = *(const float4*)(g4b - GS);
  float4 AstB = *(const float4*)(g4b - 2 * GS);
  *(float4*)&ringb[0 * 256 + lane * 4] = vb0;
  *(float4*)&ringb[1 * 256 + lane * 4] = vb1;
  float cf0 = __expf(ringf[0 + lane]),   cf1 = __expf(ringf[64 + lane]),
        cf2 = __expf(ringf[128 + lane]), cf3 = __expf(ringf[192 + lane]);
  float cb0 = __expf(ringb[0 + lane]),   cb1 = __expf(ringb[64 + lane]),
        cb2 = __expf(ringb[128 + lane]), cb3 = __expf(ringb[192 + lane]);

  // ---- fused main loop: one wave advances BOTH directions per step ----
  int g = 0;
  for (; g < Gmin; ++g) {
    *(float4*)&ringf[((g + 2) & 3) * 256 + lane * 4] = AstF;
    AstF = *(const float4*)(g4f + (size_t)(g + 3) * GS);       // slice <= m+12 < 1024
    *(float4*)&ringb[((g + 2) & 3) * 256 + lane * 4] = AstB;
    AstB = *(const float4*)(g4b - (size_t)(g + 3) * GS);       // slice >= m-11 >= 0
    const int s1 = ((g + 1) & 3) * 256;
    float nf0 = ringf[s1 + lane],       nf1 = ringf[s1 + 64 + lane],
          nf2 = ringf[s1 + 128 + lane], nf3 = ringf[s1 + 192 + lane];
    float nb0 = ringb[s1 + lane],       nb1 = ringb[s1 + 64 + lane],
          nb2 = ringb[s1 + 128 + lane], nb3 = ringb[s1 + 192 + lane];
    DSTEP(u, v, cf0, cb0); DSTEP(u, v, cf1, cb1);
    DSTEP(u, v, cf2, cb2); DSTEP(u, v, cf3, cb3);
    RESCALE0(u, Lkf); RESCALE0(v, Lkb);
    cf0 = __expf(nf0); cf1 = __expf(nf1); cf2 = __expf(nf2); cf3 = __expf(nf3);
    cb0 = __expf(nb0); cb1 = __expf(nb1); cb2 = __expf(nb2); cb3 = __expf(nb3);
  }

  // ---- fwd continuation (Gf - Gmin <= 1 group) + tail ----
  for (int gf = g; gf < Gf; ++gf) {
    *(float4*)&ringf[((gf + 2) & 3) * 256 + lane * 4] = AstF;
    AstF = *(const float4*)(g4f + (size_t)(gf + 3) * GS);
    const int s1 = ((gf + 1) & 3) * 256;
    float nf0 = ringf[s1 + lane],       nf1 = ringf[s1 + 64 + lane],
          nf2 = ringf[s1 + 128 + lane], nf3 = ringf[s1 + 192 + lane];
    FSTEP_LIN(u, cf0); FSTEP_LIN(u, cf1); FSTEP_LIN(u, cf2); FSTEP_LIN(u, cf3);
    RESCALE0(u, Lkf);
    cf0 = __expf(nf0); cf1 = __expf(nf1); cf2 = __expf(nf2); cf3 = __expf(nf3);
  }
  if (rf > 0) { FSTEP_LIN(u, cf0); }
  if (rf > 1) { FSTEP_LIN(u, cf1); }
  if (rf > 2) { FSTEP_LIN(u, cf2); }
  RESCALE(u, Lkf);                                    // exact normalize

  // ---- bwd continuation + tail ----
  for (int gb = g; gb < Gb; ++gb) {
    *(float4*)&ringb[((gb + 2) & 3) * 256 + lane * 4] = AstB;
    AstB = *(const float4*)(g4b - (size_t)(gb + 3) * GS);
    const int s1 = ((gb + 1) & 3) * 256;
    float nb0 = ringb[s1 + lane],       nb1 = ringb[s1 + 64 + lane],
          nb2 = ringb[s1 + 128 + lane], nb3 = ringb[s1 + 192 + lane];
    BSTEP_LIN(v, cb0); BSTEP_LIN(v, cb1); BSTEP_LIN(v, cb2); BSTEP_LIN(v, cb3);
    RESCALE0(v, Lkb);
    cb0 = __expf(nb0); cb1 = __expf(nb1); cb2 = __expf(nb2); cb3 = __expf(nb3);
  }
  if (rb > 0) { BSTEP_LIN(v, cb0); }
  if (rb > 1) { BSTEP_LIN(v, cb1); }
  if (rb > 2) { BSTEP_LIN(v, cb2); }
  RESCALE(v, Lkb);                                    // exact normalize

  // ---- meet-point combine: same wave, pure registers ----
  float p = u * v;                                    // max ~4, positive terms
  float ssum = wred_sum(p);
  if (lane == 0) {
    float logZ = __logf(ssum) + shf + shb + (float)(Lkf + Lkb) * LN2F;
    out[bc] = sc + sc_ht - logZ;
  }
}

extern "C" void kernel_launch(void* const* d_in, const int* in_sizes, int n_in,
                              void* d_out, int out_size, void* d_ws, size_t ws_size,
                              hipStream_t stream) {
  const float* em      = (const float*)d_in[0];
  const int*   tags    = (const int*)d_in[1];
  const int*   lengths = (const int*)d_in[2];
  const float* trans   = (const float*)d_in[3];
  const float* head    = (const float*)d_in[4];
  const float* tail    = (const float*)d_in[5];
  float* out = (float*)d_out;
  crf_fwd<<<dim3(Bn * Cn), dim3(64), 0, stream>>>(em, tags, lengths, trans, head, tail, out);
}

// Round 13
// 204.014 us; speedup vs baseline: 2.2400x; 2.2400x over previous
//
#include <hip/hip_runtime.h>
#include <cstdint>
#include <cstddef>

#define Tn 1024
#define Bn 64
#define Cn 8
#define Nn 64
#define LDP 65             /* padded row stride for trans_lds */
#define TBC 512            /* tags stride per t */
#define ES 32768           /* emissions stride per t (B*C*N) */
#define GS ((size_t)4 * ES)  /* group stride: 4 t-slices */
#define LN2F 0.69314718056f

// ---- wave64 reductions via DPP ----
__device__ __forceinline__ float wred_max(float x) {
  int v;
#define STEP(ctrl) \
  v = __builtin_amdgcn_update_dpp((int)0xff800000, __float_as_int(x), ctrl, 0xf, 0xf, false); \
  x = fmaxf(x, __int_as_float(v));
  STEP(0x111) STEP(0x112) STEP(0x114) STEP(0x118) STEP(0x142) STEP(0x143)
#undef STEP
  return __int_as_float(__builtin_amdgcn_readlane(__float_as_int(x), 63));
}

__device__ __forceinline__ float wred_sum(float x) {
  int v;
#define STEP(ctrl) \
  v = __builtin_amdgcn_update_dpp(0, __float_as_int(x), ctrl, 0xf, 0xf, false); \
  x = x + __int_as_float(v);
  STEP(0x111) STEP(0x112) STEP(0x114) STEP(0x118) STEP(0x142) STEP(0x143)
#undef STEP
  return __int_as_float(__builtin_amdgcn_readlane(__float_as_int(x), 63));
}

__device__ __forceinline__ float lane0(float x) {
  return __int_as_float(__builtin_amdgcn_readlane(__float_as_int(x), 0));
}

// ---- batched-readlane 64x64 matvec: NO memory ops on the chain ----
// r7 proved readlane matvec exact but paid ~11cy SALU hazard per
// readlane->fma pair (interleaved). Batch-16: all 16 readlanes issue first,
// then 16 FMAs — every SGPR consumer is >=16 instrs after its producer, so
// the wait-states retire for free. P is never address-taken (stays in VGPRs).
#define RL(k) __builtin_amdgcn_readlane(Ei_, (k))
#define MB16(base) \
  { int t0_=RL(base+0), t1_=RL(base+1), t2_=RL(base+2),  t3_=RL(base+3), \
        t4_=RL(base+4), t5_=RL(base+5), t6_=RL(base+6),  t7_=RL(base+7), \
        t8_=RL(base+8), t9_=RL(base+9), t10_=RL(base+10),t11_=RL(base+11), \
        t12_=RL(base+12),t13_=RL(base+13),t14_=RL(base+14),t15_=RL(base+15); \
    a0_ = fmaf(__int_as_float(t0_),  P[base+0],  a0_); \
    a1_ = fmaf(__int_as_float(t1_),  P[base+1],  a1_); \
    a2_ = fmaf(__int_as_float(t2_),  P[base+2],  a2_); \
    a3_ = fmaf(__int_as_float(t3_),  P[base+3],  a3_); \
    a4_ = fmaf(__int_as_float(t4_),  P[base+4],  a4_); \
    a5_ = fmaf(__int_as_float(t5_),  P[base+5],  a5_); \
    a6_ = fmaf(__int_as_float(t6_),  P[base+6],  a6_); \
    a7_ = fmaf(__int_as_float(t7_),  P[base+7],  a7_); \
    a0_ = fmaf(__int_as_float(t8_),  P[base+8],  a0_); \
    a1_ = fmaf(__int_as_float(t9_),  P[base+9],  a1_); \
    a2_ = fmaf(__int_as_float(t10_), P[base+10], a2_); \
    a3_ = fmaf(__int_as_float(t11_), P[base+11], a3_); \
    a4_ = fmaf(__int_as_float(t12_), P[base+12], a4_); \
    a5_ = fmaf(__int_as_float(t13_), P[base+13], a5_); \
    a6_ = fmaf(__int_as_float(t14_), P[base+14], a6_); \
    a7_ = fmaf(__int_as_float(t15_), P[base+15], a7_); }

#define MV64_BODY() \
  float a0_=0.f, a1_=0.f, a2_=0.f, a3_=0.f, a4_=0.f, a5_=0.f, a6_=0.f, a7_=0.f; \
  MB16(0) MB16(16) MB16(32) MB16(48) \
  float s_ = ((a0_+a1_) + (a2_+a3_)) + ((a4_+a5_) + (a6_+a7_));

// Linear-space forward step: u'_j = w_j * sum_i P_ij u_i   (P = e^{trans})
#define FSTEP_LIN(u, wv) do {                       \
    int Ei_ = __float_as_int(u);                    \
    MV64_BODY();                                    \
    (u) = s_ * (wv);                                \
  } while (0)

// Linear-space backward step: v_i = sum_j P_ij (w_j v'_j)
#define BSTEP_LIN(v, wv) do {                       \
    int Ei_ = __float_as_int((v) * (wv));           \
    MV64_BODY();                                    \
    (v) = s_;                                       \
  } while (0)

// r8-verified per-group rescale (lane0 exponent, exact 2^-k, integer Lk).
#define RESCALE0(u, Lk) do {                        \
    int ke_ = (__builtin_amdgcn_readlane(__float_as_int(u), 0) >> 23) & 255; \
    (Lk) += ke_ - 127;                              \
    (u) *= __int_as_float((254 - ke_) << 23);       \
  } while (0)

// Exact max-based rescale (epilogue only).
#define RESCALE(u, Lk) do {                         \
    float mx_ = wred_max(u);                        \
    int ke_ = (__float_as_int(mx_) >> 23) & 255;    \
    (Lk) += ke_ - 127;                              \
    (u) *= __int_as_float((254 - ke_) << 23);       \
  } while (0)

__global__ __launch_bounds__(128, 1)
void crf_fwd(const float* __restrict__ em, const int* __restrict__ tags,
             const int* __restrict__ lengths, const float* __restrict__ trans,
             const float* __restrict__ head, const float* __restrict__ tail,
             float* __restrict__ out) {
  __shared__ float trans_lds[Nn * LDP];               // 16.6 KB
  __shared__ __align__(16) float ring[2][4 * 4 * Nn]; // per-wave 4-group em ring
  __shared__ float blds[Nn];
  __shared__ float scw[2];
  __shared__ float sc_ht;
  __shared__ float lbshift;

  const int bid = blockIdx.x;                         // 512 = B*C chains
  const int b = bid >> 3, c = bid & 7;
  const int tid = threadIdx.x;
  const int w = __builtin_amdgcn_readfirstlane(tid >> 6);  // 0 = fwd, 1 = bwd
  const int lane = tid & 63;
  const int bc = b * Cn + c;
  const int len = lengths[b];                         // [512, 1024]
  const int m = len >> 1;

  // ---- stage transitions[c] into LDS, stride 65 ----
  const float* tc = trans + c * Nn * Nn;
  for (int k = tid; k < Nn * Nn; k += 128) trans_lds[(k >> 6) * LDP + (k & 63)] = tc[k];
  __syncthreads();

  // ---- log_scores phase ----
  float sc = 0.f;
#pragma unroll
  for (int it = 0; it < 8; ++it) {
    int t = it * 128 + tid;
    if (t < len) {
      int tagc = tags[t * TBC + bc];
      sc += em[(size_t)t * ES + (size_t)bc * Nn + tagc];
      if (t >= 1) {
        int tagp = tags[(t - 1) * TBC + bc];
        sc += trans_lds[tagp * LDP + tagc];
      }
    }
  }
  sc = wred_sum(sc);
  if (lane == 0) scw[w] = sc;
  if (tid == 0) {
    int tag0 = tags[bc];
    int tagl = tags[(len - 1) * TBC + bc];
    sc_ht = head[c * Nn + tag0] + tail[c * Nn + tagl];
  }

  // ---- per-wave P fragment (r7-verified layout): fwd = column, bwd = row ----
  float P[64];
  if (w == 0) {
#pragma unroll
    for (int k = 0; k < 64; ++k) P[k] = __expf(trans_lds[k * LDP + lane]);
  } else {
#pragma unroll
    for (int k = 0; k < 64; ++k) P[k] = __expf(trans_lds[lane * LDP + k]);
  }

  float* myring = ring[w];
  float state = 0.f;
  float shift0 = 0.f;
  int   Lk = 0;

  if (w == 0) {
    // ======== forward: steps i=0..m-1 consume em slice t=1+i ========
    float al0 = head[c * Nn + lane] + em[(size_t)bc * Nn + lane];
    shift0 = lane0(al0);
    float u = __expf(al0 - shift0);
    const float* g4 = em + (size_t)(1 + (lane >> 4)) * ES + (size_t)bc * Nn + ((lane & 15) << 2);
    const int ns = m, G = ns >> 2, r = ns & 3;

    float4 v0 = *(const float4*)(g4);
    float4 v1 = *(const float4*)(g4 + GS);
    float4 Ast = *(const float4*)(g4 + 2 * GS);
    *(float4*)&myring[0 * 256 + lane * 4] = v0;
    *(float4*)&myring[1 * 256 + lane * 4] = v1;
    float c0 = __expf(myring[0 * 256 +   0 + lane]), c1 = __expf(myring[0 * 256 +  64 + lane]),
          c2 = __expf(myring[0 * 256 + 128 + lane]), c3 = __expf(myring[0 * 256 + 192 + lane]);

    for (int g = 0; g < G; ++g) {
      *(float4*)&myring[((g + 2) & 3) * 256 + lane * 4] = Ast;   // commit group g+2
      Ast = *(const float4*)(g4 + (size_t)(g + 3) * GS);         // fetch group g+3 (slice <= m+12 < 1024)
      const int s1 = ((g + 1) & 3) * 256;
      float n0 = myring[s1 + lane],       n1 = myring[s1 + 64 + lane],
            n2 = myring[s1 + 128 + lane], n3 = myring[s1 + 192 + lane];
      FSTEP_LIN(u, c0); FSTEP_LIN(u, c1); FSTEP_LIN(u, c2); FSTEP_LIN(u, c3);
      RESCALE0(u, Lk);
      c0 = __expf(n0); c1 = __expf(n1); c2 = __expf(n2); c3 = __expf(n3);
    }
    if (r > 0) { FSTEP_LIN(u, c0); }
    if (r > 1) { FSTEP_LIN(u, c1); }
    if (r > 2) { FSTEP_LIN(u, c2); }
    RESCALE(u, Lk);                                   // exact normalize at meet point
    state = u;                                        // u_m = e^{alpha_m - A0 - Lk*ln2}
  } else {
    // ======== backward: steps k=0..nb-1 consume em slice len-1-k ========
    float tl = tail[c * Nn + lane];
    shift0 = lane0(tl);
    float v = __expf(tl - shift0);
    const int ns = len - 1 - m, G = ns >> 2, r = ns & 3;
    const float* g4 = em + (size_t)(len - 1 - (lane >> 4)) * ES + (size_t)bc * Nn + ((lane & 15) << 2);

    float4 v0 = *(const float4*)(g4);
    float4 v1 = *(const float4*)(g4 - GS);
    float4 Ast = *(const float4*)(g4 - 2 * GS);
    *(float4*)&myring[0 * 256 + lane * 4] = v0;
    *(float4*)&myring[1 * 256 + lane * 4] = v1;
    float c0 = __expf(myring[0 * 256 +   0 + lane]), c1 = __expf(myring[0 * 256 +  64 + lane]),
          c2 = __expf(myring[0 * 256 + 128 + lane]), c3 = __expf(myring[0 * 256 + 192 + lane]);

    for (int g = 0; g < G; ++g) {
      *(float4*)&myring[((g + 2) & 3) * 256 + lane * 4] = Ast;
      Ast = *(const float4*)(g4 - (size_t)(g + 3) * GS);         // slice >= m-11 >= 0
      const int s1 = ((g + 1) & 3) * 256;
      float n0 = myring[s1 + lane],       n1 = myring[s1 + 64 + lane],
            n2 = myring[s1 + 128 + lane], n3 = myring[s1 + 192 + lane];
      BSTEP_LIN(v, c0); BSTEP_LIN(v, c1); BSTEP_LIN(v, c2); BSTEP_LIN(v, c3);
      RESCALE0(v, Lk);
      c0 = __expf(n0); c1 = __expf(n1); c2 = __expf(n2); c3 = __expf(n3);
    }
    if (r > 0) { BSTEP_LIN(v, c0); }
    if (r > 1) { BSTEP_LIN(v, c1); }
    if (r > 2) { BSTEP_LIN(v, c2); }
    RESCALE(v, Lk);                                   // exact normalize at meet point
    blds[lane] = v;                                   // v_m = e^{beta_m - B0 - Lk*ln2}
    if (lane == 0) lbshift = shift0 + (float)Lk * LN2F;
  }

  __syncthreads();                                    // both waves hit exactly once

  if (w == 0) {
    float p = state * blds[lane];                     // max ~4, positive terms
    float ssum = wred_sum(p);
    if (lane == 0) {
      float logZ = __logf(ssum) + shift0 + (float)Lk * LN2F + lbshift;
      out[bc] = scw[0] + scw[1] + sc_ht - logZ;
    }
  }
}

extern "C" void kernel_launch(void* const* d_in, const int* in_sizes, int n_in,
                              void* d_out, int out_size, void* d_ws, size_t ws_size,
                              hipStream_t stream) {
  const float* em      = (const float*)d_in[0];
  const int*   tags    = (const int*)d_in[1];
  const int*   lengths = (const int*)d_in[2];
  const float* trans   = (const float*)d_in[3];
  const float* head    = (const float*)d_in[4];
  const float* tail    = (const float*)d_in[5];
  float* out = (float*)d_out;
  crf_fwd<<<dim3(Bn * Cn), dim3(128), 0, stream>>>(em, tags, lengths, trans, head, tail, out);
}